// Round 1
// baseline (126.089 us; speedup 1.0000x reference)
//
#include <hip/hip_runtime.h>

#define B_SZ 16
#define N_BOX 2048
#define AH 256
#define AW 256

// ---------------------------------------------------------------------------
// Kernel 1: rasterize boxes -> integer rects, build sorted-batch range table,
// zero the output accumulator.
// ---------------------------------------------------------------------------
__global__ __launch_bounds__(256) void prep_kernel(
    const float* __restrict__ target,   // [N_BOX, 6]
    const int*   __restrict__ img_h_p,  // scalar
    const int*   __restrict__ img_w_p,  // scalar
    int4*        __restrict__ rects,    // [N_BOX] (X1,Y1,X2,Y2); empty if invalid
    int*         __restrict__ starts,   // [B_SZ+1]
    float*       __restrict__ out)      // [1]
{
    int i = blockIdx.x * blockDim.x + threadIdx.x;
    if (i == 0) out[0] = 0.0f;   // harness re-poisons d_out to 0xAA each call
    if (i >= N_BOX) return;

    float fh = (float)img_h_p[0];
    float fw = (float)img_w_p[0];

    const float* t = target + (size_t)i * 6;
    float xc = t[2], yc = t[3], bw = t[4], bh = t[5];

    // exact replication of reference float32 math (bw/2 == bw*0.5f exactly)
    float x1 = fw * (xc - bw * 0.5f);
    float y1 = fh * (yc - bh * 0.5f);
    float x2 = fw * (xc + bw * 0.5f);
    float y2 = fh * (yc + bh * 0.5f);

    bool valid = (x1 <= fw) && (y1 <= fh) && (x2 <= fw) && (y2 <= fh);

    float sx = (float)AW / fw;   // 0.25 exactly for 256/1024
    float sy = (float)AH / fh;

    int X1 = (int)fmaxf(truncf(x1 * sx), 0.0f);
    int Y1 = (int)fmaxf(truncf(y1 * sy), 0.0f);
    int X2 = (int)fminf(ceilf(x2 * sx) + 1.0f, (float)AW);
    int Y2 = (int)fminf(ceilf(y2 * sy) + 1.0f, (float)AH);

    if (!valid) { X1 = 0; X2 = 0; Y1 = 0; Y2 = 0; }  // empty rect
    rects[i] = make_int4(X1, Y1, X2, Y2);

    // bidx is sorted; thread i owns boundary entries (prev_b, b]
    int b  = (int)t[0];
    int bp = (i == 0) ? -1 : (int)target[(size_t)(i - 1) * 6];
    for (int k = bp + 1; k <= b; ++k) starts[k] = i;
    if (i == N_BOX - 1)
        for (int k = b + 1; k <= B_SZ; ++k) starts[k] = N_BOX;
}

// ---------------------------------------------------------------------------
// Kernel 2: one block per (batch, row). Stage batch rects in LDS (chunked),
// pre-filter on this block's y, OR coverage per x, BCE, block-reduce,
// one atomicAdd per block (gated on has_box).
// ---------------------------------------------------------------------------
__global__ __launch_bounds__(256) void bce_kernel(
    const float* __restrict__ mask,    // [B_SZ,1,AH,AW]
    const int4*  __restrict__ rects,
    const int*   __restrict__ starts,
    float*       __restrict__ out)
{
    const int b = blockIdx.y;
    const int y = blockIdx.x;
    const int x = threadIdx.x;

    __shared__ int2  s_xr[256];   // (X1,X2) of boxes whose Y-range covers y
    __shared__ float s_red[4];

    const int s   = starts[b];
    const int e   = starts[b + 1];
    const int cnt = e - s;

    bool covered = false;
    for (int base = 0; base < cnt; base += 256) {
        const int rem = min(256, cnt - base);
        __syncthreads();
        if (x < rem) {
            int4 r = rects[s + base + x];
            // pre-filter on row: if y outside [Y1,Y2) store empty interval
            s_xr[x] = (y >= r.y && y < r.w) ? make_int2(r.x, r.z)
                                            : make_int2(0, 0);
        }
        __syncthreads();
        for (int j = 0; j < rem; ++j) {
            int2 r = s_xr[j];                  // LDS broadcast (same addr)
            covered = covered || (x >= r.x && x < r.y);
        }
    }

    const float l = mask[((size_t)b * AH + y) * AW + x];
    const float m = covered ? 1.0f : 0.0f;
    float bce = fmaxf(l, 0.0f) - l * m + log1pf(expf(-fabsf(l)));

    // wave (64-lane) shuffle reduction, then cross-wave via LDS
    float v = bce;
    #pragma unroll
    for (int off = 32; off > 0; off >>= 1) v += __shfl_down(v, off, 64);
    const int wave = x >> 6;
    if ((x & 63) == 0) s_red[wave] = v;
    __syncthreads();
    if (x == 0) {
        float sum = s_red[0] + s_red[1] + s_red[2] + s_red[3];
        if (cnt > 0)   // has_box: any box with this bidx (valid or not)
            atomicAdd(out, sum * (1.0f / (float)(AH * AW)));
    }
}

extern "C" void kernel_launch(void* const* d_in, const int* in_sizes, int n_in,
                              void* d_out, int out_size, void* d_ws, size_t ws_size,
                              hipStream_t stream) {
    const float* attention_mask = (const float*)d_in[0];
    const float* target         = (const float*)d_in[1];
    const int*   img_h          = (const int*)d_in[3];
    const int*   img_w          = (const int*)d_in[4];

    int4* rects  = (int4*)d_ws;
    int*  starts = (int*)((char*)d_ws + (size_t)N_BOX * sizeof(int4));
    float* out   = (float*)d_out;

    prep_kernel<<<(N_BOX + 255) / 256, 256, 0, stream>>>(
        target, img_h, img_w, rects, starts, out);

    dim3 grid(AH, B_SZ);
    bce_kernel<<<grid, 256, 0, stream>>>(attention_mask, rects, starts, out);
}

// Round 2
// 87.970 us; speedup vs baseline: 1.4333x; 1.4333x over previous
//
#include <hip/hip_runtime.h>

#define B_SZ 16
#define N_BOX 2048
#define AH 256
#define AW 256
#define ROWS 4            // rows per block in bce_kernel

// ---------------------------------------------------------------------------
// Kernel 1: rasterize boxes -> integer rects, build sorted-batch range table,
// zero the output accumulator.
// ---------------------------------------------------------------------------
__global__ __launch_bounds__(256) void prep_kernel(
    const float* __restrict__ target,   // [N_BOX, 6]
    const int*   __restrict__ img_h_p,  // scalar
    const int*   __restrict__ img_w_p,  // scalar
    int4*        __restrict__ rects,    // [N_BOX] (X1,Y1,X2,Y2); empty if invalid
    int*         __restrict__ starts,   // [B_SZ+1]
    float*       __restrict__ out)      // [1]
{
    int i = blockIdx.x * blockDim.x + threadIdx.x;
    if (i == 0) out[0] = 0.0f;   // harness re-poisons d_out to 0xAA each call
    if (i >= N_BOX) return;

    float fh = (float)img_h_p[0];
    float fw = (float)img_w_p[0];

    const float* t = target + (size_t)i * 6;
    float xc = t[2], yc = t[3], bw = t[4], bh = t[5];

    // exact replication of reference float32 math
    float x1 = fw * (xc - bw * 0.5f);
    float y1 = fh * (yc - bh * 0.5f);
    float x2 = fw * (xc + bw * 0.5f);
    float y2 = fh * (yc + bh * 0.5f);

    bool valid = (x1 <= fw) && (y1 <= fh) && (x2 <= fw) && (y2 <= fh);

    float sx = (float)AW / fw;
    float sy = (float)AH / fh;

    int X1 = (int)fmaxf(truncf(x1 * sx), 0.0f);
    int Y1 = (int)fmaxf(truncf(y1 * sy), 0.0f);
    int X2 = (int)fminf(ceilf(x2 * sx) + 1.0f, (float)AW);
    int Y2 = (int)fminf(ceilf(y2 * sy) + 1.0f, (float)AH);

    if (!valid) { X1 = 0; X2 = 0; Y1 = 0; Y2 = 0; }  // empty rect
    rects[i] = make_int4(X1, Y1, X2, Y2);

    // bidx is sorted; thread i owns boundary entries (prev_b, b]
    int b  = (int)t[0];
    int bp = (i == 0) ? -1 : (int)target[(size_t)(i - 1) * 6];
    for (int k = bp + 1; k <= b; ++k) starts[k] = i;
    if (i == N_BOX - 1)
        for (int k = b + 1; k <= B_SZ; ++k) starts[k] = N_BOX;
}

// ---------------------------------------------------------------------------
// Kernel 2: one block per (batch, 4-row strip). Box loop reads rects with a
// wave-uniform index -> compiler emits batched scalar loads (SMEM) and a
// scalar branch for the y-reject; per-thread work is ~4 VALU per passing box.
// One reduction + one atomicAdd per block.
// ---------------------------------------------------------------------------
__global__ __launch_bounds__(256) void bce_kernel(
    const float* __restrict__ mask,    // [B_SZ,1,AH,AW]
    const int4*  __restrict__ rects,
    const int*   __restrict__ starts,
    float*       __restrict__ out)
{
    const int b  = blockIdx.y;
    const int y0 = blockIdx.x * ROWS;
    const int x  = threadIdx.x;

    __shared__ float s_red[4];

    const int s   = starts[b];
    const int e   = starts[b + 1];
    const int cnt = e - s;

    unsigned cov = 0;                  // bit r: pixel (y0+r, x) covered
    for (int j = s; j < e; ++j) {
        const int4 r = rects[j];       // uniform index -> s_load_dwordx4
        // scalar y-reject: does [r.y, r.w) intersect [y0, y0+ROWS)?
        if (r.y < y0 + ROWS && r.w > y0) {
            // row bits are wave-uniform (SALU)
            const int lo = max(r.y - y0, 0);
            const int hi = min(r.w - y0, ROWS);
            const unsigned rowbits = ((1u << (hi - lo)) - 1u) << lo;
            const bool xin = (x >= r.x) && (x < r.z);
            cov |= xin ? rowbits : 0u; // v_cndmask + v_or
        }
    }

    float acc = 0.0f;
    #pragma unroll
    for (int r = 0; r < ROWS; ++r) {
        const float l = mask[((size_t)b * AH + (y0 + r)) * AW + x];
        const float m = (float)((cov >> r) & 1u);
        acc += fmaxf(l, 0.0f) - l * m + log1pf(expf(-fabsf(l)));
    }

    // wave (64-lane) shuffle reduction, then cross-wave via LDS
    #pragma unroll
    for (int off = 32; off > 0; off >>= 1) acc += __shfl_down(acc, off, 64);
    const int wave = x >> 6;
    if ((x & 63) == 0) s_red[wave] = acc;
    __syncthreads();
    if (x == 0) {
        const float sum = s_red[0] + s_red[1] + s_red[2] + s_red[3];
        if (cnt > 0)   // has_box gate
            atomicAdd(out, sum * (1.0f / (float)(AH * AW)));
    }
}

extern "C" void kernel_launch(void* const* d_in, const int* in_sizes, int n_in,
                              void* d_out, int out_size, void* d_ws, size_t ws_size,
                              hipStream_t stream) {
    const float* attention_mask = (const float*)d_in[0];
    const float* target         = (const float*)d_in[1];
    const int*   img_h          = (const int*)d_in[3];
    const int*   img_w          = (const int*)d_in[4];

    int4* rects  = (int4*)d_ws;
    int*  starts = (int*)((char*)d_ws + (size_t)N_BOX * sizeof(int4));
    float* out   = (float*)d_out;

    prep_kernel<<<(N_BOX + 255) / 256, 256, 0, stream>>>(
        target, img_h, img_w, rects, starts, out);

    dim3 grid(AH / ROWS, B_SZ);
    bce_kernel<<<grid, 256, 0, stream>>>(attention_mask, rects, starts, out);
}

// Round 3
// 76.289 us; speedup vs baseline: 1.6528x; 1.1531x over previous
//
#include <hip/hip_runtime.h>

#define B_SZ 16
#define N_BOX 2048
#define AH 256
#define AW 256
#define W_PER_ROW (AW / 32)              // 8 u32 words per row
#define COVER_WORDS (B_SZ * AH * W_PER_ROW)
#define PX_PER_THREAD 16
#define PX_PER_BLOCK (256 * PX_PER_THREAD)  // 4096

// ---------------------------------------------------------------------------
// Kernel 1: one wave per box. Rasterize the box directly into a 1-bit
// coverage mask (16 x 256 x 256 bits in d_ws) via atomicOr; set has_box[b];
// zero the output scalar. Rect math replicates the jnp float32 reference.
// ---------------------------------------------------------------------------
__global__ __launch_bounds__(256) void raster_kernel(
    const float* __restrict__ target,   // [N_BOX, 6]
    const int*   __restrict__ img_h_p,
    const int*   __restrict__ img_w_p,
    unsigned*    __restrict__ cover,    // [B_SZ*AH*W_PER_ROW] (pre-zeroed)
    int*         __restrict__ has_box,  // [B_SZ] (pre-zeroed)
    float*       __restrict__ out)      // [1]
{
    if (blockIdx.x == 0 && threadIdx.x == 0) out[0] = 0.0f;

    const int box  = blockIdx.x * (blockDim.x >> 6) + (threadIdx.x >> 6);
    const int lane = threadIdx.x & 63;
    if (box >= N_BOX) return;

    const float fh = (float)img_h_p[0];
    const float fw = (float)img_w_p[0];

    const float* t = target + (size_t)box * 6;   // uniform per wave -> s_loads
    const int   b  = (int)t[0];
    const float xc = t[2], yc = t[3], bw = t[4], bh = t[5];

    if (lane == 0) has_box[b] = 1;   // all writers store 1; plain store is safe

    float x1 = fw * (xc - bw * 0.5f);
    float y1 = fh * (yc - bh * 0.5f);
    float x2 = fw * (xc + bw * 0.5f);
    float y2 = fh * (yc + bh * 0.5f);

    const bool valid = (x1 <= fw) && (y1 <= fh) && (x2 <= fw) && (y2 <= fh);

    const float sx = (float)AW / fw;
    const float sy = (float)AH / fh;

    const int X1 = (int)fmaxf(truncf(x1 * sx), 0.0f);
    int       Y1 = (int)fmaxf(truncf(y1 * sy), 0.0f);
    const int X2 = (int)fminf(ceilf(x2 * sx) + 1.0f, (float)AW);
    int       Y2 = (int)fminf(ceilf(y2 * sy) + 1.0f, (float)AH);

    if (!valid || X1 >= X2) { Y1 = 0; Y2 = 0; }   // empty

    for (int r = Y1 + lane; r < Y2; r += 64) {
        unsigned* row = cover + ((size_t)b * AH + r) * W_PER_ROW;
        const int w0 = X1 >> 5;
        const int w1 = (X2 - 1) >> 5;
        for (int w = w0; w <= w1; ++w) {
            const unsigned lo = (w == w0) ? (unsigned)(X1 & 31) : 0u;
            const unsigned hi = (w == w1) ? (unsigned)((X2 - 1) & 31) : 31u;
            const unsigned bits =
                ((hi == 31u) ? 0xFFFFFFFFu : ((1u << (hi + 1)) - 1u)) &
                ~((1u << lo) - 1u);
            atomicOr(row + w, bits);
        }
    }
}

// ---------------------------------------------------------------------------
// Kernel 2: pure streaming BCE. 256 blocks; each thread handles 16 pixels
// (4 x float4 loads) + one coverage-word read. Block-reduce, one gated
// atomicAdd per block. Each block lies entirely within one batch image.
// ---------------------------------------------------------------------------
__global__ __launch_bounds__(256) void bce_kernel(
    const float*    __restrict__ mask,     // [B_SZ,1,AH,AW]
    const unsigned* __restrict__ cover,
    const int*      __restrict__ has_box,
    float*          __restrict__ out)
{
    const int b = blockIdx.x >> 4;                       // 16 blocks / batch
    const size_t pix0 = (size_t)blockIdx.x * PX_PER_BLOCK
                      + (size_t)threadIdx.x * PX_PER_THREAD;

    const int p   = (int)(pix0 & (AH * AW - 1));         // within-image index
    const int row = p >> 8;
    const int x   = p & 255;                             // multiple of 16

    const unsigned wbits =
        cover[((size_t)b * AH + row) * W_PER_ROW + (x >> 5)] >> (x & 31);

    const float4* m4 = (const float4*)(mask + pix0);
    float acc = 0.0f;
    #pragma unroll
    for (int k = 0; k < 4; ++k) {
        const float4 v = m4[k];
        const float l0 = v.x, l1 = v.y, l2 = v.z, l3 = v.w;
        const float m0 = (float)((wbits >> (4 * k + 0)) & 1u);
        const float m1 = (float)((wbits >> (4 * k + 1)) & 1u);
        const float m2 = (float)((wbits >> (4 * k + 2)) & 1u);
        const float m3 = (float)((wbits >> (4 * k + 3)) & 1u);
        acc += fmaxf(l0, 0.0f) - l0 * m0 + log1pf(expf(-fabsf(l0)));
        acc += fmaxf(l1, 0.0f) - l1 * m1 + log1pf(expf(-fabsf(l1)));
        acc += fmaxf(l2, 0.0f) - l2 * m2 + log1pf(expf(-fabsf(l2)));
        acc += fmaxf(l3, 0.0f) - l3 * m3 + log1pf(expf(-fabsf(l3)));
    }

    __shared__ float s_red[4];
    #pragma unroll
    for (int off = 32; off > 0; off >>= 1) acc += __shfl_down(acc, off, 64);
    const int wave = threadIdx.x >> 6;
    if ((threadIdx.x & 63) == 0) s_red[wave] = acc;
    __syncthreads();
    if (threadIdx.x == 0) {
        const float sum = s_red[0] + s_red[1] + s_red[2] + s_red[3];
        if (has_box[b])
            atomicAdd(out, sum * (1.0f / (float)(AH * AW)));
    }
}

extern "C" void kernel_launch(void* const* d_in, const int* in_sizes, int n_in,
                              void* d_out, int out_size, void* d_ws, size_t ws_size,
                              hipStream_t stream) {
    const float* attention_mask = (const float*)d_in[0];
    const float* target         = (const float*)d_in[1];
    const int*   img_h          = (const int*)d_in[3];
    const int*   img_w          = (const int*)d_in[4];

    unsigned* cover   = (unsigned*)d_ws;
    int*      has_box = (int*)((char*)d_ws + COVER_WORDS * sizeof(unsigned));
    float*    out     = (float*)d_out;

    // zero coverage bitmask (128 KB) + has_box (64 B); capturable memset node
    hipMemsetAsync(d_ws, 0, COVER_WORDS * sizeof(unsigned) + B_SZ * sizeof(int),
                   stream);

    raster_kernel<<<N_BOX / 4, 256, 0, stream>>>(
        target, img_h, img_w, cover, has_box, out);

    bce_kernel<<<(B_SZ * AH * AW) / PX_PER_BLOCK, 256, 0, stream>>>(
        attention_mask, cover, has_box, out);
}